// Round 10
// baseline (84.807 us; speedup 1.0000x reference)
//
#include <hip/hip_runtime.h>
#include <hip/hip_bf16.h>
#include <stdint.h>

#define BB 2
#define SS 2048
#define DD 512
#define PP 13
#define TT 5
#define MH 64
#define MM (BB*SS)      // 4096 rows
#define NV (TT*DD)      // 2560
#define KK 512
#define CHUNK 16
#define NCH (SS/CHUNK)  // 128

typedef __attribute__((ext_vector_type(4))) float f32x4;
typedef __attribute__((ext_vector_type(8))) short s8v;
typedef unsigned int u32;
typedef __attribute__((address_space(3))) u32 lds_u32_t;
typedef __attribute__((address_space(1))) const u32 glb_u32_t;

__device__ __forceinline__ float bf2f(unsigned short u){
  union { unsigned int i; float f; } c; c.i = ((unsigned int)u) << 16; return c.f;
}
__device__ __forceinline__ unsigned short f2bf(float f){
  union { float f; unsigned int i; } c; c.f = f;
  unsigned int x = c.i;
  unsigned int r = (x + 0x7fffu + ((x >> 16) & 1u)) >> 16;
  return (unsigned short)r;
}
// async global->LDS, 16B per lane; LDS dest is wave-uniform base + lane*16
__device__ __forceinline__ void gld16(unsigned short* l, const unsigned short* g){
  __builtin_amdgcn_global_load_lds((glb_u32_t*)g, (lds_u32_t*)l, 16, 0, 0);
}

// ---------------------------------------------------------------- merged gate + LN + weight-prep (one launch, independent block ranges)
// [0,64): gate (inline LN + W1->LDS 32KB half-tiles + MFMA -> alpha)
// [64,1088): LayerNorm 4 rows/blk -> xn bf16
// [1088,1216): WvT = mix-contracted W_in^T bf16 + b_v
// [1216,1344): WoT bf16
__global__ __launch_bounds__(256) void k_prep_ln(
    const float* __restrict__ hs,
    const float* __restrict__ gamma, const float* __restrict__ beta,
    const float* __restrict__ W_in, const float* __restrict__ b_in,
    const float* __restrict__ mix,  const float* __restrict__ W_out,
    const float* __restrict__ W1,   const float* __restrict__ b1,
    const float* __restrict__ W2,   const float* __restrict__ b2,
    const float* __restrict__ ltau,
    unsigned short* __restrict__ xn_bf,
    unsigned short* __restrict__ W_vT, float* __restrict__ b_v,
    unsigned short* __restrict__ W_outT,
    float* __restrict__ alpha)
{
  __shared__ unsigned short W1L[MH][256];   // 32 KB, [n][k-half], 16B-slot XOR swizzle
  int blk = blockIdx.x;
  if (blk < 64){
    // ---- gate: 64 rows per block
    int gb = blk;
    int tid = threadIdx.x, lane = tid & 63, w = tid >> 6;
    int lr = lane & 15, kq = lane >> 4;
    int row = gb*64 + w*16 + lr;
    // inline LN for this lane's k-slice (k = kq*8 + kt*32 + j)
    float v[16][8];
    float s = 0.f, sq = 0.f;
    const float* xr = hs + (size_t)row*DD + kq*8;
    #pragma unroll
    for (int kt=0;kt<16;++kt){
      float4 a0 = *(const float4*)(xr + kt*32);
      float4 a1 = *(const float4*)(xr + kt*32 + 4);
      v[kt][0]=a0.x; v[kt][1]=a0.y; v[kt][2]=a0.z; v[kt][3]=a0.w;
      v[kt][4]=a1.x; v[kt][5]=a1.y; v[kt][6]=a1.z; v[kt][7]=a1.w;
      s  += a0.x+a0.y+a0.z+a0.w + a1.x+a1.y+a1.z+a1.w;
      sq += a0.x*a0.x+a0.y*a0.y+a0.z*a0.z+a0.w*a0.w
          + a1.x*a1.x+a1.y*a1.y+a1.z*a1.z+a1.w*a1.w;
    }
    s  += __shfl_xor(s,16);  s  += __shfl_xor(s,32);
    sq += __shfl_xor(sq,16); sq += __shfl_xor(sq,32);
    float mu   = s  * (1.f/DD);
    float var  = sq * (1.f/DD) - mu*mu;
    float rstd = rsqrtf(var + 1e-5f);
    s8v af[16];
    #pragma unroll
    for (int kt=0;kt<16;++kt){
      float4 g0 = *(const float4*)(gamma + kq*8 + kt*32);
      float4 g1 = *(const float4*)(gamma + kq*8 + kt*32 + 4);
      float4 t0 = *(const float4*)(beta  + kq*8 + kt*32);
      float4 t1 = *(const float4*)(beta  + kq*8 + kt*32 + 4);
      union { unsigned short us[8]; s8v v8; } o;
      o.us[0] = f2bf((v[kt][0]-mu)*rstd*g0.x + t0.x);
      o.us[1] = f2bf((v[kt][1]-mu)*rstd*g0.y + t0.y);
      o.us[2] = f2bf((v[kt][2]-mu)*rstd*g0.z + t0.z);
      o.us[3] = f2bf((v[kt][3]-mu)*rstd*g0.w + t0.w);
      o.us[4] = f2bf((v[kt][4]-mu)*rstd*g1.x + t1.x);
      o.us[5] = f2bf((v[kt][5]-mu)*rstd*g1.y + t1.y);
      o.us[6] = f2bf((v[kt][6]-mu)*rstd*g1.z + t1.z);
      o.us[7] = f2bf((v[kt][7]-mu)*rstd*g1.w + t1.w);
      af[kt] = o.v8;
    }
    f32x4 acc[4];
    #pragma unroll
    for (int ni=0;ni<4;++ni) acc[ni] = (f32x4){0.f,0.f,0.f,0.f};
    #pragma unroll
    for (int half=0; half<2; ++half){
      __syncthreads();   // all waves done reading previous half
      // stage W1 half (f32 [k][64]) -> W1L bf16 [n][k_local] swizzled; coalesced reads
      #pragma unroll 4
      for (int i=0;i<64;++i){
        int idx = i*256 + tid;        // = k_local*64 + n
        int n = idx & 63, kl = idx >> 6;
        int slot = (kl >> 3) ^ (n & 7);
        W1L[n][slot*8 + (kl & 7)] = f2bf(W1[(size_t)(half*256 + kl)*MH + n]);
      }
      __syncthreads();
      #pragma unroll
      for (int ktl=0;ktl<8;++ktl){
        #pragma unroll
        for (int ni=0;ni<4;++ni){
          int n = ni*16 + lr;
          int slot = (ktl*4 + kq) ^ (n & 7);
          union { uint4 u; s8v v8; } bfr;
          bfr.u = *(const uint4*)&W1L[n][slot*8];
          acc[ni] = __builtin_amdgcn_mfma_f32_16x16x32_bf16(af[half*8+ktl], bfr.v8, acc[ni], 0,0,0);
        }
      }
    }
    // epilogue (C/D: col=lane&15 -> h, row=(lane>>4)*4+reg)
    float z1[4][4];
    #pragma unroll
    for (int ni=0;ni<4;++ni){
      float bb = b1[ni*16+lr];
      #pragma unroll
      for (int r=0;r<4;++r) z1[r][ni] = tanhf(acc[ni][r] + bb);
    }
    float et[TT];
    #pragma unroll
    for (int t=0;t<TT;++t) et[t] = expf(-ltau[t]);
    float av[4][TT];
    #pragma unroll
    for (int t=0;t<TT;++t){
      float w2v[4];
      #pragma unroll
      for (int ni=0;ni<4;++ni) w2v[ni] = W2[(ni*16+lr)*TT + t];
      #pragma unroll
      for (int r=0;r<4;++r){
        float p = z1[r][0]*w2v[0] + z1[r][1]*w2v[1] + z1[r][2]*w2v[2] + z1[r][3]*w2v[3];
        #pragma unroll
        for (int o=8;o>0;o>>=1) p += __shfl_xor(p, o);
        float z2 = p + b2[t];
        float gate = 1.f/(1.f + expf(-z2));
        av[r][t] = expf(-gate * et[t]);
      }
    }
    if (lr < TT){
      int t = lr;
      #pragma unroll
      for (int r=0;r<4;++r){
        int orow = gb*64 + w*16 + kq*4 + r;
        alpha[(size_t)orow*TT + t] = av[r][t];
      }
    }
  } else if (blk < 1088){
    int tid = threadIdx.x;
    int lane = tid & 63;
    int row = (blk-64)*4 + (tid>>6);
    const float* x = hs + (size_t)row*DD + lane*8;
    float4 v0 = *(const float4*)x;
    float4 v1 = *(const float4*)(x+4);
    float s  = v0.x+v0.y+v0.z+v0.w + v1.x+v1.y+v1.z+v1.w;
    float sq = v0.x*v0.x+v0.y*v0.y+v0.z*v0.z+v0.w*v0.w
             + v1.x*v1.x+v1.y*v1.y+v1.z*v1.z+v1.w*v1.w;
    #pragma unroll
    for (int o=32;o>0;o>>=1){ s += __shfl_xor(s,o); sq += __shfl_xor(sq,o); }
    float mu   = s  * (1.f/DD);
    float var  = sq * (1.f/DD) - mu*mu;
    float rstd = rsqrtf(var + 1e-5f);
    float4 g0 = *(const float4*)(gamma + lane*8);
    float4 g1 = *(const float4*)(gamma + lane*8 + 4);
    float4 b0 = *(const float4*)(beta  + lane*8);
    float4 b1v = *(const float4*)(beta + lane*8 + 4);
    union { unsigned short us[8]; uint4 u; } pk;
    pk.us[0] = f2bf((v0.x-mu)*rstd*g0.x + b0.x);
    pk.us[1] = f2bf((v0.y-mu)*rstd*g0.y + b0.y);
    pk.us[2] = f2bf((v0.z-mu)*rstd*g0.z + b0.z);
    pk.us[3] = f2bf((v0.w-mu)*rstd*g0.w + b0.w);
    pk.us[4] = f2bf((v1.x-mu)*rstd*g1.x + b1v.x);
    pk.us[5] = f2bf((v1.y-mu)*rstd*g1.y + b1v.y);
    pk.us[6] = f2bf((v1.z-mu)*rstd*g1.z + b1v.z);
    pk.us[7] = f2bf((v1.w-mu)*rstd*g1.w + b1v.w);
    *(uint4*)(xn_bf + (size_t)row*DD + lane*8) = pk.u;
  } else if (blk < 1216){
    int idx = (blk-1088) * 256 + threadIdx.x;   // 32768 total
    int d  = idx & (DD-1);
    int k0 = idx >> 9;                   // 0..63 (8 k's each)
    float mx[PP][TT];
    #pragma unroll
    for (int p=0;p<PP;++p)
      #pragma unroll
      for (int t=0;t<TT;++t) mx[p][t] = mix[p*TT+t];
    float acc[TT][8];
    #pragma unroll
    for (int t=0;t<TT;++t)
      #pragma unroll
      for (int j=0;j<8;++j) acc[t][j] = 0.f;
    #pragma unroll
    for (int j=0;j<8;++j){
      int k = k0*8 + j;
      const float* wrow = W_in + (size_t)k * (PP*DD) + d;
      #pragma unroll
      for (int p=0;p<PP;++p){
        float w = wrow[p*DD];
        #pragma unroll
        for (int t=0;t<TT;++t) acc[t][j] += mx[p][t]*w;
      }
    }
    #pragma unroll
    for (int t=0;t<TT;++t){
      union { unsigned short us[8]; uint4 u; } pk;
      #pragma unroll
      for (int j=0;j<8;++j) pk.us[j] = f2bf(acc[t][j]);
      *(uint4*)(W_vT + ((size_t)(t*DD+d))*KK + k0*8) = pk.u;
    }
    if (k0 == 0){
      #pragma unroll
      for (int t=0;t<TT;++t){
        float s = 0.f;
        #pragma unroll
        for (int p=0;p<PP;++p) s += mx[p][t]*b_in[p*DD+d];
        b_v[t*DD+d] = s;
      }
    }
  } else {
    int idx = (blk-1216)*256 + threadIdx.x; // 32768
    int n  = idx & (DD-1);
    int k0 = idx >> 9;
    union { unsigned short us[8]; uint4 u; } pk;
    #pragma unroll
    for (int j=0;j<8;++j) pk.us[j] = f2bf(W_out[(size_t)(k0*8+j)*DD + n]);
    *(uint4*)(W_outT + (size_t)n*KK + k0*8) = pk.u;
  }
}

// ---------------------------------------------------------------- bf16 MFMA GEMM: counted-vmcnt 2-barrier dbuf + LDS XOR swizzle + XCD swizzle
template<int BN, int NDIM, bool OUTEPI>
__global__ __launch_bounds__(256, 4) void k_gemm(
    const unsigned short* __restrict__ A,
    const unsigned short* __restrict__ Bt,
    const float* __restrict__ bias,
    const float* __restrict__ hidden,
    const float* __restrict__ scale_p,
    float* __restrict__ outF,
    unsigned short* __restrict__ outBf)
{
  constexpr int NI  = (BN == 128) ? 4 : 2;
  constexpr int WNT = BN / 2;
  constexpr int NLD = (BN == 128) ? 4 : 3;   // gld16 per wave per stage
  __shared__ unsigned short lA[2][128*32];
  __shared__ unsigned short lB[2][BN*32];
  // XCD swizzle: contiguous bm-chunks per XCD (nwg % 8 == 0 for both grids)
  int bid = blockIdx.y * gridDim.x + blockIdx.x;
  int nwg = gridDim.x * gridDim.y;
  int swz = (bid & 7) * (nwg >> 3) + (bid >> 3);
  int bn = swz % gridDim.x, bm = swz / gridDim.x;
  int tid  = threadIdx.x;
  int lane = tid & 63;
  int w    = tid >> 6;
  int wm = w >> 1, wn = w & 1;
  f32x4 acc[4][NI];
  #pragma unroll
  for (int i=0;i<4;++i)
    #pragma unroll
    for (int j=0;j<NI;++j) acc[i][j] = (f32x4){0.f,0.f,0.f,0.f};

  int srow  = lane >> 2;                       // 0..15
  int slotS = (lane & 3) ^ (srow & 3);         // inverse-swizzled global k-slot
  const uint8_t* gA = (const uint8_t*)(A + (size_t)(bm*128 + w*32 + srow)*KK) + slotS*16;
  const uint8_t* gB;
  if constexpr (BN == 128) gB = (const uint8_t*)(Bt + (size_t)(bn*BN + w*32 + srow)*KK) + slotS*16;
  else                     gB = (const uint8_t*)(Bt + (size_t)(bn*BN + w*16 + srow)*KK) + slotS*16;
  int lr = lane & 15, kq = lane >> 4;
  int kqs = kq ^ (lr & 3);                     // swizzled read slot

  auto stage = [&](int buf, int kt){
    int off = kt*64;  // bytes
    gld16(&lA[buf][(w*32)*32],    (const unsigned short*)(gA + off));
    gld16(&lA[buf][(w*32+16)*32], (const unsigned short*)(gA + (size_t)16*KK*2 + off));
    if constexpr (BN == 128){
      gld16(&lB[buf][(w*32)*32],    (const unsigned short*)(gB + off));
      gld16(&lB[buf][(w*32+16)*32], (const unsigned short*)(gB + (size_t)16*KK*2 + off));
    } else {
      gld16(&lB[buf][(w*16)*32],    (const unsigned short*)(gB + off));
    }
  };
  auto compute = [&](int buf){
    union { uint4 u; s8v v; } af[4], bfr[NI];
    #pragma unroll
    for (int mi=0;mi<4;++mi) af[mi].u  = *(const uint4*)&lA[buf][(wm*64+mi*16+lr)*32 + kqs*8];
    #pragma unroll
    for (int ni=0;ni<NI;++ni) bfr[ni].u = *(const uint4*)&lB[buf][(wn*WNT+ni*16+lr)*32 + kqs*8];
    #pragma unroll
    for (int mi=0;mi<4;++mi)
      #pragma unroll
      for (int ni=0;ni<NI;++ni)
        acc[mi][ni] = __builtin_amdgcn_mfma_f32_16x16x32_bf16(af[mi].v, bfr[ni].v, acc[mi][ni], 0,0,0);
  };

  stage(0, 0);
  #pragma unroll
  for (int kt=0; kt<16; ++kt){
    if (kt < 15){
      stage((kt+1)&1, kt+1);
      // wait only own PREVIOUS-tile loads (the NLD just-issued stay in flight)
      if constexpr (NLD == 4) asm volatile("s_waitcnt vmcnt(4)" ::: "memory");
      else                    asm volatile("s_waitcnt vmcnt(3)" ::: "memory");
    } else {
      asm volatile("s_waitcnt vmcnt(0)" ::: "memory");
    }
    __builtin_amdgcn_sched_barrier(0);
    __builtin_amdgcn_s_barrier();          // barrier1: tile kt visible to all waves
    __builtin_amdgcn_sched_barrier(0);
    compute(kt&1);
    __builtin_amdgcn_sched_barrier(0);
    __builtin_amdgcn_s_barrier();          // barrier2: all waves done reading buf kt&1
  }

  float sc = 0.f;
  if constexpr (OUTEPI) sc = *scale_p;
  #pragma unroll
  for (int mi=0;mi<4;++mi){
    #pragma unroll
    for (int ni=0;ni<NI;++ni){
      int row = bm*128 + wm*64 + mi*16 + kq*4;   // C/D: col=lane&15, row=(lane>>4)*4+reg
      int col = bn*BN  + wn*WNT + ni*16 + lr;
      float bs = bias[col];
      f32x4 c = acc[mi][ni];
      #pragma unroll
      for (int r=0;r<4;++r){
        float val = c[r] + bs;
        size_t off = (size_t)(row+r)*NDIM + col;
        if constexpr (OUTEPI) outF[off] = hidden[off] + sc*val;
        else                  outBf[off] = f2bf(val);
      }
    }
  }
}

// ---------------------------------------------------------------- scan phase A: block=(b,chunk), wave per t, lane owns 8 d.
// Scans v in registers; emits y_loc (bf16, via LDS transpose), L (chunk-end, bf16), PA.
__global__ __launch_bounds__(320) void k_scan_a(
    const float* __restrict__ alpha,
    const unsigned short* __restrict__ v,
    unsigned short* __restrict__ L, float* __restrict__ PA,
    unsigned short* __restrict__ yloc)
{
  int blk = blockIdx.x;           // b*NCH + c
  int c = blk & (NCH-1), b = blk >> 7;
  int tid = threadIdx.x;          // 320 = 5 waves
  int t  = tid >> 6;              // wave = t
  int d8 = tid & 63;              // 8 consecutive d
  __shared__ float sAl[CHUNK*TT];
  __shared__ unsigned short yl[TT][8][DD];   // 40 KB
  if (tid < CHUNK*TT) sAl[tid] = alpha[(size_t)(b*SS + c*CHUNK)*TT + tid];
  __syncthreads();
  const unsigned short* vp = v + (size_t)(b*SS + c*CHUNK)*NV + t*DD + d8*8;
  float g[8];
  #pragma unroll
  for (int j=0;j<8;++j) g[j] = 0.f;
  float pa = 1.f;
  #pragma unroll
  for (int half=0; half<2; ++half){
    uint4 vv[8];
    #pragma unroll
    for (int s=0;s<8;++s) vv[s] = *(const uint4*)(vp + (size_t)(half*8+s)*NV);
    #pragma unroll
    for (int s=0;s<8;++s){
      float a = sAl[(half*8+s)*TT+t], om = 1.f - a;
      const unsigned short* pv = (const unsigned short*)&vv[s];
      union { unsigned short us[8]; uint4 u; } o;
      #pragma unroll
      for (int j=0;j<8;++j){ g[j] = a*g[j] + om*bf2f(pv[j]); o.us[j] = f2bf(g[j]); }
      *(uint4*)&yl[t][s][d8*8] = o.u;
      pa *= a;
    }
    __syncthreads();
    if (t < 4){
      #pragma unroll
      for (int ii=0; ii<2; ++ii){
        int s = t*2 + ii;
        float y[8];
        #pragma unroll
        for (int j=0;j<8;++j) y[j] = 0.f;
        #pragma unroll
        for (int tt=0;tt<TT;++tt){
          uint4 gv = *(const uint4*)&yl[tt][s][d8*8];
          const unsigned short* gp = (const unsigned short*)&gv;
          #pragma unroll
          for (int j=0;j<8;++j) y[j] += bf2f(gp[j]);
        }
        union { unsigned short us[8]; uint4 u; } o;
        #pragma unroll
        for (int j=0;j<8;++j) o.us[j] = f2bf(y[j]);
        *(uint4*)(yloc + (size_t)(b*SS + c*CHUNK + half*8 + s)*DD + d8*8) = o.u;
      }
    }
    __syncthreads();
  }
  union { unsigned short us[8]; uint4 u; } lo;
  #pragma unroll
  for (int j=0;j<8;++j) lo.us[j] = f2bf(g[j]);
  *(uint4*)(L + ((size_t)(b*TT+t)*NCH + c)*DD + d8*8) = lo.u;
  if (d8 == 0) PA[(size_t)(b*TT+t)*NCH + c] = pa;
}

// ---------------------------------------------------------------- scan phase B: sequential carry over chunks; 20 blocks (b,t,d-half), 16-deep prefetch
__global__ __launch_bounds__(256) void k_scan_b(
    const float* __restrict__ mix,
    const float* __restrict__ h_prev,
    const float* __restrict__ PA,
    const unsigned short* __restrict__ L,
    unsigned short* __restrict__ Gc)
{
  int blk = blockIdx.x;      // (b*TT + t)*2 + dhalf
  int bt = blk >> 1;
  int t = bt % TT, b = bt / TT;
  int d = (blk & 1)*256 + threadIdx.x;
  __shared__ float sP[NCH];
  if (threadIdx.x < NCH) sP[threadIdx.x] = PA[(size_t)bt*NCH + threadIdx.x];
  __syncthreads();
  float carry = 0.f;         // g_init = sum_p mix[p,t]*h_prev[b,p,t,d]
  #pragma unroll
  for (int p=0;p<PP;++p)
    carry += mix[p*TT+t] * h_prev[((size_t)(b*PP+p)*TT + t)*DD + d];
  const unsigned short* Lp = L  + (size_t)bt*NCH*DD + d;
  unsigned short*       gc = Gc + (size_t)bt*NCH*DD + d;
  float buf[16], nbuf[16];
  #pragma unroll
  for (int j=0;j<16;++j) buf[j] = bf2f(Lp[(size_t)j*DD]);
  for (int c0=0;c0<NCH;c0+=16){
    if (c0+16 < NCH){
      #pragma unroll
      for (int j=0;j<16;++j) nbuf[j] = bf2f(Lp[(size_t)(c0+16+j)*DD]);
    }
    #pragma unroll
    for (int j=0;j<16;++j){
      gc[(size_t)(c0+j)*DD] = f2bf(carry);
      carry = sP[c0+j]*carry + buf[j];
    }
    #pragma unroll
    for (int j=0;j<16;++j) buf[j] = nbuf[j];
  }
}

// ---------------------------------------------------------------- scan phase C: y(s) = y_loc(s) + sum_t pref_t(s)*carry_t
__global__ __launch_bounds__(256) void k_scan_c(
    const float* __restrict__ alpha,
    const unsigned short* __restrict__ yloc,
    const unsigned short* __restrict__ Gc,
    unsigned short* __restrict__ ybf)
{
  int blk = blockIdx.x;           // b*NCH + c
  int c = blk & (NCH-1), b = blk >> 7;
  int tid = threadIdx.x;          // 256 = 4 waves
  int s4 = tid >> 6;              // wave covers steps s4*4 .. s4*4+3
  int d8 = tid & 63;
  __shared__ float sAl[CHUNK*TT];
  if (tid < CHUNK*TT) sAl[tid] = alpha[(size_t)(b*SS + c*CHUNK)*TT + tid];
  __syncthreads();
  float ca[TT][8];
  #pragma unroll
  for (int t=0;t<TT;++t){
    uint4 gv = *(const uint4*)(Gc + ((size_t)(b*TT+t)*NCH + c)*DD + d8*8);
    const unsigned short* gp = (const unsigned short*)&gv;
    #pragma unroll
    for (int j=0;j<8;++j) ca[t][j] = bf2f(gp[j]);
  }
  float pr[TT];
  #pragma unroll
  for (int t=0;t<TT;++t){
    float p = 1.f;
    for (int j=0;j<s4*4;++j) p *= sAl[j*TT+t];
    pr[t] = p;
  }
  const unsigned short* yp = yloc + (size_t)(b*SS + c*CHUNK)*DD + d8*8;
  unsigned short* op = ybf + (size_t)(b*SS + c*CHUNK)*DD + d8*8;
  #pragma unroll
  for (int i=0;i<4;++i){
    int s2 = s4*4 + i;
    uint4 yv = *(const uint4*)(yp + (size_t)s2*DD);
    const unsigned short* yq = (const unsigned short*)&yv;
    float y[8];
    #pragma unroll
    for (int j=0;j<8;++j) y[j] = bf2f(yq[j]);
    #pragma unroll
    for (int t=0;t<TT;++t){
      pr[t] *= sAl[s2*TT+t];
      #pragma unroll
      for (int j=0;j<8;++j) y[j] += pr[t]*ca[t][j];
    }
    union { unsigned short us[8]; uint4 u; } o;
    #pragma unroll
    for (int j=0;j<8;++j) o.us[j] = f2bf(y[j]);
    *(uint4*)(op + (size_t)s2*DD) = o.u;
  }
}

// ----------------------------------------------------------------
extern "C" void kernel_launch(void* const* d_in, const int* in_sizes, int n_in,
                              void* d_out, int out_size, void* d_ws, size_t ws_size,
                              hipStream_t stream)
{
  (void)in_sizes; (void)n_in; (void)out_size; (void)ws_size;
  const float* hs     = (const float*)d_in[0];
  const float* gamma  = (const float*)d_in[1];
  const float* beta   = (const float*)d_in[2];
  const float* W_in   = (const float*)d_in[3];
  const float* b_in   = (const float*)d_in[4];
  const float* W1     = (const float*)d_in[5];
  const float* b1     = (const float*)d_in[6];
  const float* W2     = (const float*)d_in[7];
  const float* b2     = (const float*)d_in[8];
  const float* ltau   = (const float*)d_in[9];
  const float* mix    = (const float*)d_in[10];
  const float* W_out  = (const float*)d_in[11];
  const float* b_out  = (const float*)d_in[12];
  const float* scale  = (const float*)d_in[13];
  const float* h_prev = (const float*)d_in[14];
  float* out = (float*)d_out;

  uint8_t* w = (uint8_t*)d_ws;
  unsigned short* xn   = (unsigned short*)(w);                  //  4,194,304 (reused as y_loc)
  unsigned short* WvT  = (unsigned short*)(w + 4194304);        //  2,621,440
  unsigned short* WoT  = (unsigned short*)(w + 6815744);        //    524,288
  float* alphaB        = (float*)(w + 7340032);                 //     81,920
  float* b_v           = (float*)(w + 7421952);                 //     10,240
  float* PA            = (float*)(w + 7432192);                 //      5,120
  unsigned short* L    = (unsigned short*)(w + 7437312);        //  1,310,720 (bf16)
  unsigned short* Gc   = (unsigned short*)(w + 10058752);       //  1,310,720 (bf16)
  unsigned short* vg   = (unsigned short*)(w + 12680192);       // 20,971,520
  unsigned short* ybf  = (unsigned short*)(w + 33651712);       //  4,194,304
  unsigned short* yloc = xn;    // aliased: xn dead after gemm1

  hipLaunchKernelGGL(k_prep_ln, dim3(1344), dim3(256), 0, stream,
                     hs, gamma, beta, W_in, b_in, mix, W_out, W1, b1, W2, b2, ltau,
                     xn, WvT, b_v, WoT, alphaB);
  hipLaunchKernelGGL((k_gemm<128,NV,false>), dim3(NV/128, MM/128), dim3(256), 0, stream,
                     xn, WvT, b_v, nullptr, nullptr, nullptr, vg);
  hipLaunchKernelGGL(k_scan_a, dim3(BB*NCH), dim3(320), 0, stream, alphaB, vg, L, PA, yloc);
  hipLaunchKernelGGL(k_scan_b, dim3(2*BB*TT), dim3(256), 0, stream, mix, h_prev, PA, L, Gc);
  hipLaunchKernelGGL(k_scan_c, dim3(BB*NCH), dim3(256), 0, stream, alphaB, yloc, Gc, ybf);
  hipLaunchKernelGGL((k_gemm<64,DD,true>), dim3(DD/64, MM/128), dim3(256), 0, stream,
                     ybf, WoT, b_out, hs, scale, out, nullptr);
}

// Round 11
// 80.659 us; speedup vs baseline: 1.0514x; 1.0514x over previous
//
#include <hip/hip_runtime.h>
#include <hip/hip_bf16.h>
#include <stdint.h>

#define BB 2
#define SS 2048
#define DD 512
#define PP 13
#define TT 5
#define MH 64
#define MM (BB*SS)      // 4096 rows
#define NV (TT*DD)      // 2560
#define KK 512
#define CHUNK 16
#define NCH (SS/CHUNK)  // 128

typedef __attribute__((ext_vector_type(4))) float f32x4;
typedef __attribute__((ext_vector_type(8))) short s8v;
typedef unsigned int u32;
typedef __attribute__((address_space(3))) u32 lds_u32_t;
typedef __attribute__((address_space(1))) const u32 glb_u32_t;

__device__ __forceinline__ float bf2f(unsigned short u){
  union { unsigned int i; float f; } c; c.i = ((unsigned int)u) << 16; return c.f;
}
__device__ __forceinline__ unsigned short f2bf(float f){
  union { float f; unsigned int i; } c; c.f = f;
  unsigned int x = c.i;
  unsigned int r = (x + 0x7fffu + ((x >> 16) & 1u)) >> 16;
  return (unsigned short)r;
}
// async global->LDS, 16B per lane; LDS dest is wave-uniform base + lane*16
__device__ __forceinline__ void gld16(unsigned short* l, const unsigned short* g){
  __builtin_amdgcn_global_load_lds((glb_u32_t*)g, (lds_u32_t*)l, 16, 0, 0);
}

// ---------------------------------------------------------------- merged gate + LN + weight-prep (one launch, independent block ranges)
// [0,64): gate (self-sufficient: inline LN + W1->LDS transpose + MFMA -> alpha)
// [64,1088): LayerNorm 4 rows/blk -> xn bf16
// [1088,1216): WvT = mix-contracted W_in^T bf16 + b_v
// [1216,1344): WoT bf16
__global__ __launch_bounds__(256) void k_prep_ln(
    const float* __restrict__ hs,
    const float* __restrict__ gamma, const float* __restrict__ beta,
    const float* __restrict__ W_in, const float* __restrict__ b_in,
    const float* __restrict__ mix,  const float* __restrict__ W_out,
    const float* __restrict__ W1,   const float* __restrict__ b1,
    const float* __restrict__ W2,   const float* __restrict__ b2,
    const float* __restrict__ ltau,
    unsigned short* __restrict__ xn_bf,
    unsigned short* __restrict__ W_vT, float* __restrict__ b_v,
    unsigned short* __restrict__ W_outT,
    float* __restrict__ alpha)
{
  __shared__ unsigned short W1L[MH][KK];   // 64 KB, [n][k], 16B-slot XOR swizzle
  int blk = blockIdx.x;
  if (blk < 64){
    // ---- gate: 64 rows per block
    int gb = blk;
    int tid = threadIdx.x, lane = tid & 63, w = tid >> 6;
    int lr = lane & 15, kq = lane >> 4;
    int row = gb*64 + w*16 + lr;
    // stage W1 (f32 [k][n]) -> W1L bf16 [n][k] swizzled; coalesced reads
    #pragma unroll 4
    for (int i=0;i<128;++i){
      int idx = i*256 + tid;        // = k*64 + n
      int n = idx & 63, k = idx >> 6;
      int slot = (k >> 3) ^ (n & 7);
      W1L[n][slot*8 + (k & 7)] = f2bf(W1[idx]);
    }
    // inline LN for this lane's k-slice (k = kq*8 + kt*32 + j)
    float v[16][8];
    float s = 0.f, sq = 0.f;
    const float* xr = hs + (size_t)row*DD + kq*8;
    #pragma unroll
    for (int kt=0;kt<16;++kt){
      float4 a0 = *(const float4*)(xr + kt*32);
      float4 a1 = *(const float4*)(xr + kt*32 + 4);
      v[kt][0]=a0.x; v[kt][1]=a0.y; v[kt][2]=a0.z; v[kt][3]=a0.w;
      v[kt][4]=a1.x; v[kt][5]=a1.y; v[kt][6]=a1.z; v[kt][7]=a1.w;
      s  += a0.x+a0.y+a0.z+a0.w + a1.x+a1.y+a1.z+a1.w;
      sq += a0.x*a0.x+a0.y*a0.y+a0.z*a0.z+a0.w*a0.w
          + a1.x*a1.x+a1.y*a1.y+a1.z*a1.z+a1.w*a1.w;
    }
    s  += __shfl_xor(s,16);  s  += __shfl_xor(s,32);
    sq += __shfl_xor(sq,16); sq += __shfl_xor(sq,32);
    float mu   = s  * (1.f/DD);
    float var  = sq * (1.f/DD) - mu*mu;
    float rstd = rsqrtf(var + 1e-5f);
    s8v af[16];
    #pragma unroll
    for (int kt=0;kt<16;++kt){
      float4 g0 = *(const float4*)(gamma + kq*8 + kt*32);
      float4 g1 = *(const float4*)(gamma + kq*8 + kt*32 + 4);
      float4 t0 = *(const float4*)(beta  + kq*8 + kt*32);
      float4 t1 = *(const float4*)(beta  + kq*8 + kt*32 + 4);
      union { unsigned short us[8]; s8v v8; } o;
      o.us[0] = f2bf((v[kt][0]-mu)*rstd*g0.x + t0.x);
      o.us[1] = f2bf((v[kt][1]-mu)*rstd*g0.y + t0.y);
      o.us[2] = f2bf((v[kt][2]-mu)*rstd*g0.z + t0.z);
      o.us[3] = f2bf((v[kt][3]-mu)*rstd*g0.w + t0.w);
      o.us[4] = f2bf((v[kt][4]-mu)*rstd*g1.x + t1.x);
      o.us[5] = f2bf((v[kt][5]-mu)*rstd*g1.y + t1.y);
      o.us[6] = f2bf((v[kt][6]-mu)*rstd*g1.z + t1.z);
      o.us[7] = f2bf((v[kt][7]-mu)*rstd*g1.w + t1.w);
      af[kt] = o.v8;
    }
    __syncthreads();
    f32x4 acc[4];
    #pragma unroll
    for (int ni=0;ni<4;++ni) acc[ni] = (f32x4){0.f,0.f,0.f,0.f};
    #pragma unroll
    for (int kt=0;kt<16;++kt){
      #pragma unroll
      for (int ni=0;ni<4;++ni){
        int n = ni*16 + lr;
        int slot = (kt*4 + kq) ^ (n & 7);
        union { uint4 u; s8v v8; } bfr;
        bfr.u = *(const uint4*)&W1L[n][slot*8];
        acc[ni] = __builtin_amdgcn_mfma_f32_16x16x32_bf16(af[kt], bfr.v8, acc[ni], 0,0,0);
      }
    }
    // epilogue (C/D: col=lane&15 -> h, row=(lane>>4)*4+reg)
    float z1[4][4];
    #pragma unroll
    for (int ni=0;ni<4;++ni){
      float bb = b1[ni*16+lr];
      #pragma unroll
      for (int r=0;r<4;++r) z1[r][ni] = tanhf(acc[ni][r] + bb);
    }
    float et[TT];
    #pragma unroll
    for (int t=0;t<TT;++t) et[t] = expf(-ltau[t]);
    float av[4][TT];
    #pragma unroll
    for (int t=0;t<TT;++t){
      float w2v[4];
      #pragma unroll
      for (int ni=0;ni<4;++ni) w2v[ni] = W2[(ni*16+lr)*TT + t];
      #pragma unroll
      for (int r=0;r<4;++r){
        float p = z1[r][0]*w2v[0] + z1[r][1]*w2v[1] + z1[r][2]*w2v[2] + z1[r][3]*w2v[3];
        #pragma unroll
        for (int o=8;o>0;o>>=1) p += __shfl_xor(p, o);
        float z2 = p + b2[t];
        float gate = 1.f/(1.f + expf(-z2));
        av[r][t] = expf(-gate * et[t]);
      }
    }
    if (lr < TT){
      int t = lr;
      #pragma unroll
      for (int r=0;r<4;++r){
        int orow = gb*64 + w*16 + kq*4 + r;
        alpha[(size_t)orow*TT + t] = av[r][t];
      }
    }
  } else if (blk < 1088){
    int tid = threadIdx.x;
    int lane = tid & 63;
    int row = (blk-64)*4 + (tid>>6);
    const float* x = hs + (size_t)row*DD + lane*8;
    float4 v0 = *(const float4*)x;
    float4 v1 = *(const float4*)(x+4);
    float s  = v0.x+v0.y+v0.z+v0.w + v1.x+v1.y+v1.z+v1.w;
    float sq = v0.x*v0.x+v0.y*v0.y+v0.z*v0.z+v0.w*v0.w
             + v1.x*v1.x+v1.y*v1.y+v1.z*v1.z+v1.w*v1.w;
    #pragma unroll
    for (int o=32;o>0;o>>=1){ s += __shfl_xor(s,o); sq += __shfl_xor(sq,o); }
    float mu   = s  * (1.f/DD);
    float var  = sq * (1.f/DD) - mu*mu;
    float rstd = rsqrtf(var + 1e-5f);
    float4 g0 = *(const float4*)(gamma + lane*8);
    float4 g1 = *(const float4*)(gamma + lane*8 + 4);
    float4 b0 = *(const float4*)(beta  + lane*8);
    float4 b1v = *(const float4*)(beta + lane*8 + 4);
    union { unsigned short us[8]; uint4 u; } pk;
    pk.us[0] = f2bf((v0.x-mu)*rstd*g0.x + b0.x);
    pk.us[1] = f2bf((v0.y-mu)*rstd*g0.y + b0.y);
    pk.us[2] = f2bf((v0.z-mu)*rstd*g0.z + b0.z);
    pk.us[3] = f2bf((v0.w-mu)*rstd*g0.w + b0.w);
    pk.us[4] = f2bf((v1.x-mu)*rstd*g1.x + b1v.x);
    pk.us[5] = f2bf((v1.y-mu)*rstd*g1.y + b1v.y);
    pk.us[6] = f2bf((v1.z-mu)*rstd*g1.z + b1v.z);
    pk.us[7] = f2bf((v1.w-mu)*rstd*g1.w + b1v.w);
    *(uint4*)(xn_bf + (size_t)row*DD + lane*8) = pk.u;
  } else if (blk < 1216){
    int idx = (blk-1088) * 256 + threadIdx.x;   // 32768 total
    int d  = idx & (DD-1);
    int k0 = idx >> 9;                   // 0..63 (8 k's each)
    float mx[PP][TT];
    #pragma unroll
    for (int p=0;p<PP;++p)
      #pragma unroll
      for (int t=0;t<TT;++t) mx[p][t] = mix[p*TT+t];
    float acc[TT][8];
    #pragma unroll
    for (int t=0;t<TT;++t)
      #pragma unroll
      for (int j=0;j<8;++j) acc[t][j] = 0.f;
    #pragma unroll
    for (int j=0;j<8;++j){
      int k = k0*8 + j;
      const float* wrow = W_in + (size_t)k * (PP*DD) + d;
      #pragma unroll
      for (int p=0;p<PP;++p){
        float w = wrow[p*DD];
        #pragma unroll
        for (int t=0;t<TT;++t) acc[t][j] += mx[p][t]*w;
      }
    }
    #pragma unroll
    for (int t=0;t<TT;++t){
      union { unsigned short us[8]; uint4 u; } pk;
      #pragma unroll
      for (int j=0;j<8;++j) pk.us[j] = f2bf(acc[t][j]);
      *(uint4*)(W_vT + ((size_t)(t*DD+d))*KK + k0*8) = pk.u;
    }
    if (k0 == 0){
      #pragma unroll
      for (int t=0;t<TT;++t){
        float s = 0.f;
        #pragma unroll
        for (int p=0;p<PP;++p) s += mx[p][t]*b_in[p*DD+d];
        b_v[t*DD+d] = s;
      }
    }
  } else {
    int idx = (blk-1216)*256 + threadIdx.x; // 32768
    int n  = idx & (DD-1);
    int k0 = idx >> 9;
    union { unsigned short us[8]; uint4 u; } pk;
    #pragma unroll
    for (int j=0;j<8;++j) pk.us[j] = f2bf(W_out[(size_t)(k0*8+j)*DD + n]);
    *(uint4*)(W_outT + (size_t)n*KK + k0*8) = pk.u;
  }
}

// ---------------------------------------------------------------- bf16 MFMA GEMM: counted-vmcnt 2-barrier dbuf + LDS XOR swizzle + XCD swizzle
// occupancy: BN=128 -> 32KB LDS -> exactly 5 blocks/CU (VGPR cap 102 >= measured 92);
//            BN=64  -> 24KB LDS -> 6 blocks/CU.
template<int BN, int NDIM, bool OUTEPI>
__global__ __launch_bounds__(256, (BN==128)?5:6) void k_gemm(
    const unsigned short* __restrict__ A,
    const unsigned short* __restrict__ Bt,
    const float* __restrict__ bias,
    const float* __restrict__ hidden,
    const float* __restrict__ scale_p,
    float* __restrict__ outF,
    unsigned short* __restrict__ outBf)
{
  constexpr int NI  = (BN == 128) ? 4 : 2;
  constexpr int WNT = BN / 2;
  constexpr int NLD = (BN == 128) ? 4 : 3;   // gld16 per wave per stage
  __shared__ unsigned short lA[2][128*32];
  __shared__ unsigned short lB[2][BN*32];
  // XCD swizzle: contiguous bm-chunks per XCD (nwg % 8 == 0 for both grids)
  int bid = blockIdx.y * gridDim.x + blockIdx.x;
  int nwg = gridDim.x * gridDim.y;
  int swz = (bid & 7) * (nwg >> 3) + (bid >> 3);
  int bn = swz % gridDim.x, bm = swz / gridDim.x;
  int tid  = threadIdx.x;
  int lane = tid & 63;
  int w    = tid >> 6;
  int wm = w >> 1, wn = w & 1;
  f32x4 acc[4][NI];
  #pragma unroll
  for (int i=0;i<4;++i)
    #pragma unroll
    for (int j=0;j<NI;++j) acc[i][j] = (f32x4){0.f,0.f,0.f,0.f};

  int srow  = lane >> 2;                       // 0..15
  int slotS = (lane & 3) ^ (srow & 3);         // inverse-swizzled global k-slot
  const uint8_t* gA = (const uint8_t*)(A + (size_t)(bm*128 + w*32 + srow)*KK) + slotS*16;
  const uint8_t* gB;
  if constexpr (BN == 128) gB = (const uint8_t*)(Bt + (size_t)(bn*BN + w*32 + srow)*KK) + slotS*16;
  else                     gB = (const uint8_t*)(Bt + (size_t)(bn*BN + w*16 + srow)*KK) + slotS*16;
  int lr = lane & 15, kq = lane >> 4;
  int kqs = kq ^ (lr & 3);                     // swizzled read slot

  auto stage = [&](int buf, int kt){
    int off = kt*64;  // bytes
    gld16(&lA[buf][(w*32)*32],    (const unsigned short*)(gA + off));
    gld16(&lA[buf][(w*32+16)*32], (const unsigned short*)(gA + (size_t)16*KK*2 + off));
    if constexpr (BN == 128){
      gld16(&lB[buf][(w*32)*32],    (const unsigned short*)(gB + off));
      gld16(&lB[buf][(w*32+16)*32], (const unsigned short*)(gB + (size_t)16*KK*2 + off));
    } else {
      gld16(&lB[buf][(w*16)*32],    (const unsigned short*)(gB + off));
    }
  };
  auto compute = [&](int buf){
    union { uint4 u; s8v v; } af[4], bfr[NI];
    #pragma unroll
    for (int mi=0;mi<4;++mi) af[mi].u  = *(const uint4*)&lA[buf][(wm*64+mi*16+lr)*32 + kqs*8];
    #pragma unroll
    for (int ni=0;ni<NI;++ni) bfr[ni].u = *(const uint4*)&lB[buf][(wn*WNT+ni*16+lr)*32 + kqs*8];
    #pragma unroll
    for (int mi=0;mi<4;++mi)
      #pragma unroll
      for (int ni=0;ni<NI;++ni)
        acc[mi][ni] = __builtin_amdgcn_mfma_f32_16x16x32_bf16(af[mi].v, bfr[ni].v, acc[mi][ni], 0,0,0);
  };

  stage(0, 0);
  #pragma unroll
  for (int kt=0; kt<16; ++kt){
    if (kt < 15){
      stage((kt+1)&1, kt+1);
      // wait only own PREVIOUS-tile loads (the NLD just-issued stay in flight)
      if constexpr (NLD == 4) asm volatile("s_waitcnt vmcnt(4)" ::: "memory");
      else                    asm volatile("s_waitcnt vmcnt(3)" ::: "memory");
    } else {
      asm volatile("s_waitcnt vmcnt(0)" ::: "memory");
    }
    __builtin_amdgcn_sched_barrier(0);
    __builtin_amdgcn_s_barrier();          // barrier1: tile kt visible to all waves
    __builtin_amdgcn_sched_barrier(0);
    compute(kt&1);
    __builtin_amdgcn_sched_barrier(0);
    __builtin_amdgcn_s_barrier();          // barrier2: all waves done reading buf kt&1
  }

  float sc = 0.f;
  if constexpr (OUTEPI) sc = *scale_p;
  #pragma unroll
  for (int mi=0;mi<4;++mi){
    #pragma unroll
    for (int ni=0;ni<NI;++ni){
      int row = bm*128 + wm*64 + mi*16 + kq*4;   // C/D: col=lane&15, row=(lane>>4)*4+reg
      int col = bn*BN  + wn*WNT + ni*16 + lr;
      float bs = bias[col];
      f32x4 c = acc[mi][ni];
      #pragma unroll
      for (int r=0;r<4;++r){
        float val = c[r] + bs;
        size_t off = (size_t)(row+r)*NDIM + col;
        if constexpr (OUTEPI) outF[off] = hidden[off] + sc*val;
        else                  outBf[off] = f2bf(val);
      }
    }
  }
}

// ---------------------------------------------------------------- scan phase A: block=(b,chunk), wave per t, lane owns 8 d.
// Scans v in registers; emits y_loc = sum_t g_loc (bf16, via LDS transpose), L (chunk-end, f32), PA.
__global__ __launch_bounds__(320) void k_scan_a(
    const float* __restrict__ alpha,
    const unsigned short* __restrict__ v,
    float* __restrict__ L, float* __restrict__ PA,
    unsigned short* __restrict__ yloc)
{
  int blk = blockIdx.x;           // b*NCH + c
  int c = blk & (NCH-1), b = blk >> 7;
  int tid = threadIdx.x;          // 320 = 5 waves
  int t  = tid >> 6;              // wave = t
  int d8 = tid & 63;              // 8 consecutive d
  __shared__ float sAl[CHUNK*TT];
  __shared__ unsigned short yl[TT][8][DD];   // 40 KB
  if (tid < CHUNK*TT) sAl[tid] = alpha[(size_t)(b*SS + c*CHUNK)*TT + tid];
  __syncthreads();
  const unsigned short* vp = v + (size_t)(b*SS + c*CHUNK)*NV + t*DD + d8*8;
  float g[8];
  #pragma unroll
  for (int j=0;j<8;++j) g[j] = 0.f;
  float pa = 1.f;
  #pragma unroll
  for (int half=0; half<2; ++half){
    uint4 vv[8];
    #pragma unroll
    for (int s=0;s<8;++s) vv[s] = *(const uint4*)(vp + (size_t)(half*8+s)*NV);
    #pragma unroll
    for (int s=0;s<8;++s){
      float a = sAl[(half*8+s)*TT+t], om = 1.f - a;
      const unsigned short* pv = (const unsigned short*)&vv[s];
      union { unsigned short us[8]; uint4 u; } o;
      #pragma unroll
      for (int j=0;j<8;++j){ g[j] = a*g[j] + om*bf2f(pv[j]); o.us[j] = f2bf(g[j]); }
      *(uint4*)&yl[t][s][d8*8] = o.u;
      pa *= a;
    }
    __syncthreads();
    if (t < 4){
      #pragma unroll
      for (int ii=0; ii<2; ++ii){
        int s = t*2 + ii;
        float y[8];
        #pragma unroll
        for (int j=0;j<8;++j) y[j] = 0.f;
        #pragma unroll
        for (int tt=0;tt<TT;++tt){
          uint4 gv = *(const uint4*)&yl[tt][s][d8*8];
          const unsigned short* gp = (const unsigned short*)&gv;
          #pragma unroll
          for (int j=0;j<8;++j) y[j] += bf2f(gp[j]);
        }
        union { unsigned short us[8]; uint4 u; } o;
        #pragma unroll
        for (int j=0;j<8;++j) o.us[j] = f2bf(y[j]);
        *(uint4*)(yloc + (size_t)(b*SS + c*CHUNK + half*8 + s)*DD + d8*8) = o.u;
      }
    }
    __syncthreads();
  }
  float* Lp = L + ((size_t)(b*TT+t)*NCH + c)*DD + d8*8;
  *(float4*)Lp     = (float4){g[0],g[1],g[2],g[3]};
  *(float4*)(Lp+4) = (float4){g[4],g[5],g[6],g[7]};
  if (d8 == 0) PA[(size_t)(b*TT+t)*NCH + c] = pa;
}

// ---------------------------------------------------------------- scan phase B: sequential carry over chunks (one block per (b,t))
__global__ __launch_bounds__(512) void k_scan_b(
    const float* __restrict__ mix,
    const float* __restrict__ h_prev,
    const float* __restrict__ PA,
    const float* __restrict__ L,
    float* __restrict__ Gc)
{
  int blk = blockIdx.x;      // b*TT + t  (10 blocks)
  int t = blk % TT, b = blk / TT;
  int d = threadIdx.x;       // 512
  __shared__ float sP[NCH];
  if (d < NCH) sP[d] = PA[(size_t)(b*TT+t)*NCH + d];
  __syncthreads();
  float carry = 0.f;         // g_init = sum_p mix[p,t]*h_prev[b,p,t,d]
  #pragma unroll
  for (int p=0;p<PP;++p)
    carry += mix[p*TT+t] * h_prev[((size_t)(b*PP+p)*TT + t)*DD + d];
  const float* Lp = L  + (size_t)(b*TT+t)*NCH*DD + d;
  float*       gc = Gc + (size_t)(b*TT+t)*NCH*DD + d;
  float buf[8], nbuf[8];
  #pragma unroll
  for (int j=0;j<8;++j) buf[j] = Lp[(size_t)j*DD];
  for (int c0=0;c0<NCH;c0+=8){
    if (c0+8 < NCH){
      #pragma unroll
      for (int j=0;j<8;++j) nbuf[j] = Lp[(size_t)(c0+8+j)*DD];
    }
    #pragma unroll
    for (int j=0;j<8;++j){
      gc[(size_t)(c0+j)*DD] = carry;
      carry = sP[c0+j]*carry + buf[j];
    }
    #pragma unroll
    for (int j=0;j<8;++j) buf[j] = nbuf[j];
  }
}

// ---------------------------------------------------------------- scan phase C: y(s) = y_loc(s) + sum_t pref_t(s)*carry_t
__global__ __launch_bounds__(256) void k_scan_c(
    const float* __restrict__ alpha,
    const unsigned short* __restrict__ yloc,
    const float* __restrict__ Gc,
    unsigned short* __restrict__ ybf)
{
  int blk = blockIdx.x;           // b*NCH + c
  int c = blk & (NCH-1), b = blk >> 7;
  int tid = threadIdx.x;          // 256 = 4 waves
  int s4 = tid >> 6;              // wave covers steps s4*4 .. s4*4+3
  int d8 = tid & 63;
  __shared__ float sAl[CHUNK*TT];
  if (tid < CHUNK*TT) sAl[tid] = alpha[(size_t)(b*SS + c*CHUNK)*TT + tid];
  __syncthreads();
  float ca[TT][8];
  #pragma unroll
  for (int t=0;t<TT;++t){
    const float* gp = Gc + ((size_t)(b*TT+t)*NCH + c)*DD + d8*8;
    float4 c0 = *(const float4*)gp;
    float4 c1 = *(const float4*)(gp+4);
    ca[t][0]=c0.x; ca[t][1]=c0.y; ca[t][2]=c0.z; ca[t][3]=c0.w;
    ca[t][4]=c1.x; ca[t][5]=c1.y; ca[t][6]=c1.z; ca[t][7]=c1.w;
  }
  float pr[TT];
  #pragma unroll
  for (int t=0;t<TT;++t){
    float p = 1.f;
    for (int j=0;j<s4*4;++j) p *= sAl[j*TT+t];
    pr[t] = p;
  }
  const unsigned short* yp = yloc + (size_t)(b*SS + c*CHUNK)*DD + d8*8;
  unsigned short* op = ybf + (size_t)(b*SS + c*CHUNK)*DD + d8*8;
  #pragma unroll
  for (int i=0;i<4;++i){
    int s2 = s4*4 + i;
    uint4 yv = *(const uint4*)(yp + (size_t)s2*DD);
    const unsigned short* yq = (const unsigned short*)&yv;
    float y[8];
    #pragma unroll
    for (int j=0;j<8;++j) y[j] = bf2f(yq[j]);
    #pragma unroll
    for (int t=0;t<TT;++t){
      pr[t] *= sAl[s2*TT+t];
      #pragma unroll
      for (int j=0;j<8;++j) y[j] += pr[t]*ca[t][j];
    }
    union { unsigned short us[8]; uint4 u; } o;
    #pragma unroll
    for (int j=0;j<8;++j) o.us[j] = f2bf(y[j]);
    *(uint4*)(op + (size_t)s2*DD) = o.u;
  }
}

// ----------------------------------------------------------------
extern "C" void kernel_launch(void* const* d_in, const int* in_sizes, int n_in,
                              void* d_out, int out_size, void* d_ws, size_t ws_size,
                              hipStream_t stream)
{
  (void)in_sizes; (void)n_in; (void)out_size; (void)ws_size;
  const float* hs     = (const float*)d_in[0];
  const float* gamma  = (const float*)d_in[1];
  const float* beta   = (const float*)d_in[2];
  const float* W_in   = (const float*)d_in[3];
  const float* b_in   = (const float*)d_in[4];
  const float* W1     = (const float*)d_in[5];
  const float* b1     = (const float*)d_in[6];
  const float* W2     = (const float*)d_in[7];
  const float* b2     = (const float*)d_in[8];
  const float* ltau   = (const float*)d_in[9];
  const float* mix    = (const float*)d_in[10];
  const float* W_out  = (const float*)d_in[11];
  const float* b_out  = (const float*)d_in[12];
  const float* scale  = (const float*)d_in[13];
  const float* h_prev = (const float*)d_in[14];
  float* out = (float*)d_out;

  uint8_t* w = (uint8_t*)d_ws;
  unsigned short* xn   = (unsigned short*)(w);                  //  4,194,304 (reused as y_loc)
  unsigned short* WvT  = (unsigned short*)(w + 4194304);        //  2,621,440
  unsigned short* WoT  = (unsigned short*)(w + 6815744);        //    524,288
  float* alphaB        = (float*)(w + 7340032);                 //     81,920
  float* b_v           = (float*)(w + 7421952);                 //     10,240
  float* PA            = (float*)(w + 7432192);                 //      5,120
  float* L             = (float*)(w + 7437312);                 //  2,621,440
  float* Gc            = (float*)(w + 10058752);                //  2,621,440
  unsigned short* vg   = (unsigned short*)(w + 12680192);       // 20,971,520
  unsigned short* ybf  = (unsigned short*)(w + 33651712);       //  4,194,304
  unsigned short* yloc = xn;    // aliased: xn dead after gemm1

  hipLaunchKernelGGL(k_prep_ln, dim3(1344), dim3(256), 0, stream,
                     hs, gamma, beta, W_in, b_in, mix, W_out, W1, b1, W2, b2, ltau,
                     xn, WvT, b_v, WoT, alphaB);
  hipLaunchKernelGGL((k_gemm<128,NV,false>), dim3(NV/128, MM/128), dim3(256), 0, stream,
                     xn, WvT, b_v, nullptr, nullptr, nullptr, vg);
  hipLaunchKernelGGL(k_scan_a, dim3(BB*NCH), dim3(320), 0, stream, alphaB, vg, L, PA, yloc);
  hipLaunchKernelGGL(k_scan_b, dim3(BB*TT), dim3(512), 0, stream, mix, h_prev, PA, L, Gc);
  hipLaunchKernelGGL(k_scan_c, dim3(BB*NCH), dim3(256), 0, stream, alphaB, yloc, Gc, ybf);
  hipLaunchKernelGGL((k_gemm<64,DD,true>), dim3(DD/64, MM/128), dim3(256), 0, stream,
                     ybf, WoT, b_out, hs, scale, out, nullptr);
}

// Round 12
// 74.884 us; speedup vs baseline: 1.1325x; 1.0771x over previous
//
#include <hip/hip_runtime.h>
#include <hip/hip_bf16.h>
#include <stdint.h>

#define BB 2
#define SS 2048
#define DD 512
#define PP 13
#define TT 5
#define MH 64
#define MM (BB*SS)      // 4096 rows
#define NV (TT*DD)      // 2560
#define KK 512
#define CHUNK 16
#define NCH (SS/CHUNK)  // 128

typedef __attribute__((ext_vector_type(4))) float f32x4;
typedef __attribute__((ext_vector_type(8))) short s8v;
typedef unsigned int u32;
typedef __attribute__((address_space(3))) u32 lds_u32_t;
typedef __attribute__((address_space(1))) const u32 glb_u32_t;

__device__ __forceinline__ float bf2f(unsigned short u){
  union { unsigned int i; float f; } c; c.i = ((unsigned int)u) << 16; return c.f;
}
__device__ __forceinline__ unsigned short f2bf(float f){
  union { float f; unsigned int i; } c; c.f = f;
  unsigned int x = c.i;
  unsigned int r = (x + 0x7fffu + ((x >> 16) & 1u)) >> 16;
  return (unsigned short)r;
}
// async global->LDS, 16B per lane; LDS dest is wave-uniform base + lane*16
__device__ __forceinline__ void gld16(unsigned short* l, const unsigned short* g){
  __builtin_amdgcn_global_load_lds((glb_u32_t*)g, (lds_u32_t*)l, 16, 0, 0);
}

// ---------------------------------------------------------------- merged gate + LN + weight-prep (one launch, independent block ranges)
// [0,64): gate (self-sufficient: inline LN + W1->LDS transpose + MFMA -> alpha)
// [64,1088): LayerNorm 4 rows/blk -> xn bf16
// [1088,1216): WvT = mix-contracted W_in^T bf16 + b_v
// [1216,1344): WoT bf16
__global__ __launch_bounds__(256) void k_prep_ln(
    const float* __restrict__ hs,
    const float* __restrict__ gamma, const float* __restrict__ beta,
    const float* __restrict__ W_in, const float* __restrict__ b_in,
    const float* __restrict__ mix,  const float* __restrict__ W_out,
    const float* __restrict__ W1,   const float* __restrict__ b1,
    const float* __restrict__ W2,   const float* __restrict__ b2,
    const float* __restrict__ ltau,
    unsigned short* __restrict__ xn_bf,
    unsigned short* __restrict__ W_vT, float* __restrict__ b_v,
    unsigned short* __restrict__ W_outT,
    float* __restrict__ alpha)
{
  __shared__ unsigned short W1L[MH][KK];   // 64 KB, [n][k], 16B-slot XOR swizzle
  int blk = blockIdx.x;
  if (blk < 64){
    // ---- gate: 64 rows per block
    int gb = blk;
    int tid = threadIdx.x, lane = tid & 63, w = tid >> 6;
    int lr = lane & 15, kq = lane >> 4;
    int row = gb*64 + w*16 + lr;
    // stage W1 (f32 [k][n]) -> W1L bf16 [n][k] swizzled; coalesced reads
    #pragma unroll 4
    for (int i=0;i<128;++i){
      int idx = i*256 + tid;        // = k*64 + n
      int n = idx & 63, k = idx >> 6;
      int slot = (k >> 3) ^ (n & 7);
      W1L[n][slot*8 + (k & 7)] = f2bf(W1[idx]);
    }
    // inline LN for this lane's k-slice (k = kq*8 + kt*32 + j)
    float v[16][8];
    float s = 0.f, sq = 0.f;
    const float* xr = hs + (size_t)row*DD + kq*8;
    #pragma unroll
    for (int kt=0;kt<16;++kt){
      float4 a0 = *(const float4*)(xr + kt*32);
      float4 a1 = *(const float4*)(xr + kt*32 + 4);
      v[kt][0]=a0.x; v[kt][1]=a0.y; v[kt][2]=a0.z; v[kt][3]=a0.w;
      v[kt][4]=a1.x; v[kt][5]=a1.y; v[kt][6]=a1.z; v[kt][7]=a1.w;
      s  += a0.x+a0.y+a0.z+a0.w + a1.x+a1.y+a1.z+a1.w;
      sq += a0.x*a0.x+a0.y*a0.y+a0.z*a0.z+a0.w*a0.w
          + a1.x*a1.x+a1.y*a1.y+a1.z*a1.z+a1.w*a1.w;
    }
    s  += __shfl_xor(s,16);  s  += __shfl_xor(s,32);
    sq += __shfl_xor(sq,16); sq += __shfl_xor(sq,32);
    float mu   = s  * (1.f/DD);
    float var  = sq * (1.f/DD) - mu*mu;
    float rstd = rsqrtf(var + 1e-5f);
    s8v af[16];
    #pragma unroll
    for (int kt=0;kt<16;++kt){
      float4 g0 = *(const float4*)(gamma + kq*8 + kt*32);
      float4 g1 = *(const float4*)(gamma + kq*8 + kt*32 + 4);
      float4 t0 = *(const float4*)(beta  + kq*8 + kt*32);
      float4 t1 = *(const float4*)(beta  + kq*8 + kt*32 + 4);
      union { unsigned short us[8]; s8v v8; } o;
      o.us[0] = f2bf((v[kt][0]-mu)*rstd*g0.x + t0.x);
      o.us[1] = f2bf((v[kt][1]-mu)*rstd*g0.y + t0.y);
      o.us[2] = f2bf((v[kt][2]-mu)*rstd*g0.z + t0.z);
      o.us[3] = f2bf((v[kt][3]-mu)*rstd*g0.w + t0.w);
      o.us[4] = f2bf((v[kt][4]-mu)*rstd*g1.x + t1.x);
      o.us[5] = f2bf((v[kt][5]-mu)*rstd*g1.y + t1.y);
      o.us[6] = f2bf((v[kt][6]-mu)*rstd*g1.z + t1.z);
      o.us[7] = f2bf((v[kt][7]-mu)*rstd*g1.w + t1.w);
      af[kt] = o.v8;
    }
    __syncthreads();
    f32x4 acc[4];
    #pragma unroll
    for (int ni=0;ni<4;++ni) acc[ni] = (f32x4){0.f,0.f,0.f,0.f};
    #pragma unroll
    for (int kt=0;kt<16;++kt){
      #pragma unroll
      for (int ni=0;ni<4;++ni){
        int n = ni*16 + lr;
        int slot = (kt*4 + kq) ^ (n & 7);
        union { uint4 u; s8v v8; } bfr;
        bfr.u = *(const uint4*)&W1L[n][slot*8];
        acc[ni] = __builtin_amdgcn_mfma_f32_16x16x32_bf16(af[kt], bfr.v8, acc[ni], 0,0,0);
      }
    }
    // epilogue (C/D: col=lane&15 -> h, row=(lane>>4)*4+reg)
    float z1[4][4];
    #pragma unroll
    for (int ni=0;ni<4;++ni){
      float bb = b1[ni*16+lr];
      #pragma unroll
      for (int r=0;r<4;++r) z1[r][ni] = tanhf(acc[ni][r] + bb);
    }
    float et[TT];
    #pragma unroll
    for (int t=0;t<TT;++t) et[t] = expf(-ltau[t]);
    float av[4][TT];
    #pragma unroll
    for (int t=0;t<TT;++t){
      float w2v[4];
      #pragma unroll
      for (int ni=0;ni<4;++ni) w2v[ni] = W2[(ni*16+lr)*TT + t];
      #pragma unroll
      for (int r=0;r<4;++r){
        float p = z1[r][0]*w2v[0] + z1[r][1]*w2v[1] + z1[r][2]*w2v[2] + z1[r][3]*w2v[3];
        #pragma unroll
        for (int o=8;o>0;o>>=1) p += __shfl_xor(p, o);
        float z2 = p + b2[t];
        float gate = 1.f/(1.f + expf(-z2));
        av[r][t] = expf(-gate * et[t]);
      }
    }
    if (lr < TT){
      int t = lr;
      #pragma unroll
      for (int r=0;r<4;++r){
        int orow = gb*64 + w*16 + kq*4 + r;
        alpha[(size_t)orow*TT + t] = av[r][t];
      }
    }
  } else if (blk < 1088){
    int tid = threadIdx.x;
    int lane = tid & 63;
    int row = (blk-64)*4 + (tid>>6);
    const float* x = hs + (size_t)row*DD + lane*8;
    float4 v0 = *(const float4*)x;
    float4 v1 = *(const float4*)(x+4);
    float s  = v0.x+v0.y+v0.z+v0.w + v1.x+v1.y+v1.z+v1.w;
    float sq = v0.x*v0.x+v0.y*v0.y+v0.z*v0.z+v0.w*v0.w
             + v1.x*v1.x+v1.y*v1.y+v1.z*v1.z+v1.w*v1.w;
    #pragma unroll
    for (int o=32;o>0;o>>=1){ s += __shfl_xor(s,o); sq += __shfl_xor(sq,o); }
    float mu   = s  * (1.f/DD);
    float var  = sq * (1.f/DD) - mu*mu;
    float rstd = rsqrtf(var + 1e-5f);
    float4 g0 = *(const float4*)(gamma + lane*8);
    float4 g1 = *(const float4*)(gamma + lane*8 + 4);
    float4 b0 = *(const float4*)(beta  + lane*8);
    float4 b1v = *(const float4*)(beta + lane*8 + 4);
    union { unsigned short us[8]; uint4 u; } pk;
    pk.us[0] = f2bf((v0.x-mu)*rstd*g0.x + b0.x);
    pk.us[1] = f2bf((v0.y-mu)*rstd*g0.y + b0.y);
    pk.us[2] = f2bf((v0.z-mu)*rstd*g0.z + b0.z);
    pk.us[3] = f2bf((v0.w-mu)*rstd*g0.w + b0.w);
    pk.us[4] = f2bf((v1.x-mu)*rstd*g1.x + b1v.x);
    pk.us[5] = f2bf((v1.y-mu)*rstd*g1.y + b1v.y);
    pk.us[6] = f2bf((v1.z-mu)*rstd*g1.z + b1v.z);
    pk.us[7] = f2bf((v1.w-mu)*rstd*g1.w + b1v.w);
    *(uint4*)(xn_bf + (size_t)row*DD + lane*8) = pk.u;
  } else if (blk < 1216){
    int idx = (blk-1088) * 256 + threadIdx.x;   // 32768 total
    int d  = idx & (DD-1);
    int k0 = idx >> 9;                   // 0..63 (8 k's each)
    float mx[PP][TT];
    #pragma unroll
    for (int p=0;p<PP;++p)
      #pragma unroll
      for (int t=0;t<TT;++t) mx[p][t] = mix[p*TT+t];
    float acc[TT][8];
    #pragma unroll
    for (int t=0;t<TT;++t)
      #pragma unroll
      for (int j=0;j<8;++j) acc[t][j] = 0.f;
    #pragma unroll
    for (int j=0;j<8;++j){
      int k = k0*8 + j;
      const float* wrow = W_in + (size_t)k * (PP*DD) + d;
      #pragma unroll
      for (int p=0;p<PP;++p){
        float w = wrow[p*DD];
        #pragma unroll
        for (int t=0;t<TT;++t) acc[t][j] += mx[p][t]*w;
      }
    }
    #pragma unroll
    for (int t=0;t<TT;++t){
      union { unsigned short us[8]; uint4 u; } pk;
      #pragma unroll
      for (int j=0;j<8;++j) pk.us[j] = f2bf(acc[t][j]);
      *(uint4*)(W_vT + ((size_t)(t*DD+d))*KK + k0*8) = pk.u;
    }
    if (k0 == 0){
      #pragma unroll
      for (int t=0;t<TT;++t){
        float s = 0.f;
        #pragma unroll
        for (int p=0;p<PP;++p) s += mx[p][t]*b_in[p*DD+d];
        b_v[t*DD+d] = s;
      }
    }
  } else {
    int idx = (blk-1216)*256 + threadIdx.x; // 32768
    int n  = idx & (DD-1);
    int k0 = idx >> 9;
    union { unsigned short us[8]; uint4 u; } pk;
    #pragma unroll
    for (int j=0;j<8;++j) pk.us[j] = f2bf(W_out[(size_t)(k0*8+j)*DD + n]);
    *(uint4*)(W_outT + (size_t)n*KK + k0*8) = pk.u;
  }
}

// ---------------------------------------------------------------- bf16 MFMA GEMM: counted-vmcnt 2-barrier dbuf + LDS XOR swizzle + XCD swizzle
template<int BN, int NDIM, bool OUTEPI>
__global__ __launch_bounds__(256, 4) void k_gemm(
    const unsigned short* __restrict__ A,
    const unsigned short* __restrict__ Bt,
    const float* __restrict__ bias,
    const float* __restrict__ hidden,
    const float* __restrict__ scale_p,
    float* __restrict__ outF,
    unsigned short* __restrict__ outBf)
{
  constexpr int NI  = (BN == 128) ? 4 : 2;
  constexpr int WNT = BN / 2;
  constexpr int NLD = (BN == 128) ? 4 : 3;   // gld16 per wave per stage
  __shared__ unsigned short lA[2][128*32];
  __shared__ unsigned short lB[2][BN*32];
  // XCD swizzle: contiguous bm-chunks per XCD (nwg % 8 == 0 for both grids)
  int bid = blockIdx.y * gridDim.x + blockIdx.x;
  int nwg = gridDim.x * gridDim.y;
  int swz = (bid & 7) * (nwg >> 3) + (bid >> 3);
  int bn = swz % gridDim.x, bm = swz / gridDim.x;
  int tid  = threadIdx.x;
  int lane = tid & 63;
  int w    = tid >> 6;
  int wm = w >> 1, wn = w & 1;
  f32x4 acc[4][NI];
  #pragma unroll
  for (int i=0;i<4;++i)
    #pragma unroll
    for (int j=0;j<NI;++j) acc[i][j] = (f32x4){0.f,0.f,0.f,0.f};

  int srow  = lane >> 2;                       // 0..15
  int slotS = (lane & 3) ^ (srow & 3);         // inverse-swizzled global k-slot
  const uint8_t* gA = (const uint8_t*)(A + (size_t)(bm*128 + w*32 + srow)*KK) + slotS*16;
  const uint8_t* gB;
  if constexpr (BN == 128) gB = (const uint8_t*)(Bt + (size_t)(bn*BN + w*32 + srow)*KK) + slotS*16;
  else                     gB = (const uint8_t*)(Bt + (size_t)(bn*BN + w*16 + srow)*KK) + slotS*16;
  int lr = lane & 15, kq = lane >> 4;
  int kqs = kq ^ (lr & 3);                     // swizzled read slot

  auto stage = [&](int buf, int kt){
    int off = kt*64;  // bytes
    gld16(&lA[buf][(w*32)*32],    (const unsigned short*)(gA + off));
    gld16(&lA[buf][(w*32+16)*32], (const unsigned short*)(gA + (size_t)16*KK*2 + off));
    if constexpr (BN == 128){
      gld16(&lB[buf][(w*32)*32],    (const unsigned short*)(gB + off));
      gld16(&lB[buf][(w*32+16)*32], (const unsigned short*)(gB + (size_t)16*KK*2 + off));
    } else {
      gld16(&lB[buf][(w*16)*32],    (const unsigned short*)(gB + off));
    }
  };
  auto compute = [&](int buf){
    union { uint4 u; s8v v; } af[4], bfr[NI];
    #pragma unroll
    for (int mi=0;mi<4;++mi) af[mi].u  = *(const uint4*)&lA[buf][(wm*64+mi*16+lr)*32 + kqs*8];
    #pragma unroll
    for (int ni=0;ni<NI;++ni) bfr[ni].u = *(const uint4*)&lB[buf][(wn*WNT+ni*16+lr)*32 + kqs*8];
    #pragma unroll
    for (int mi=0;mi<4;++mi)
      #pragma unroll
      for (int ni=0;ni<NI;++ni)
        acc[mi][ni] = __builtin_amdgcn_mfma_f32_16x16x32_bf16(af[mi].v, bfr[ni].v, acc[mi][ni], 0,0,0);
  };

  stage(0, 0);
  #pragma unroll
  for (int kt=0; kt<16; ++kt){
    if (kt < 15){
      stage((kt+1)&1, kt+1);
      // wait only own PREVIOUS-tile loads (the NLD just-issued stay in flight)
      if constexpr (NLD == 4) asm volatile("s_waitcnt vmcnt(4)" ::: "memory");
      else                    asm volatile("s_waitcnt vmcnt(3)" ::: "memory");
    } else {
      asm volatile("s_waitcnt vmcnt(0)" ::: "memory");
    }
    __builtin_amdgcn_sched_barrier(0);
    __builtin_amdgcn_s_barrier();          // barrier1: tile kt visible to all waves
    __builtin_amdgcn_sched_barrier(0);
    compute(kt&1);
    __builtin_amdgcn_sched_barrier(0);
    __builtin_amdgcn_s_barrier();          // barrier2: all waves done reading buf kt&1
  }

  float sc = 0.f;
  if constexpr (OUTEPI) sc = *scale_p;
  #pragma unroll
  for (int mi=0;mi<4;++mi){
    #pragma unroll
    for (int ni=0;ni<NI;++ni){
      int row = bm*128 + wm*64 + mi*16 + kq*4;   // C/D: col=lane&15, row=(lane>>4)*4+reg
      int col = bn*BN  + wn*WNT + ni*16 + lr;
      float bs = bias[col];
      f32x4 c = acc[mi][ni];
      #pragma unroll
      for (int r=0;r<4;++r){
        float val = c[r] + bs;
        size_t off = (size_t)(row+r)*NDIM + col;
        if constexpr (OUTEPI) outF[off] = hidden[off] + sc*val;
        else                  outBf[off] = f2bf(val);
      }
    }
  }
}

// ---------------------------------------------------------------- scan phase A: block=(b,chunk), wave per t, lane owns 8 d.
// Scans v in registers; emits y_loc = sum_t g_loc (bf16, via LDS transpose), L (chunk-end, f32), PA.
__global__ __launch_bounds__(320) void k_scan_a(
    const float* __restrict__ alpha,
    const unsigned short* __restrict__ v,
    float* __restrict__ L, float* __restrict__ PA,
    unsigned short* __restrict__ yloc)
{
  int blk = blockIdx.x;           // b*NCH + c
  int c = blk & (NCH-1), b = blk >> 7;
  int tid = threadIdx.x;          // 320 = 5 waves
  int t  = tid >> 6;              // wave = t
  int d8 = tid & 63;              // 8 consecutive d
  __shared__ float sAl[CHUNK*TT];
  __shared__ unsigned short yl[TT][8][DD];   // 40 KB
  if (tid < CHUNK*TT) sAl[tid] = alpha[(size_t)(b*SS + c*CHUNK)*TT + tid];
  __syncthreads();
  const unsigned short* vp = v + (size_t)(b*SS + c*CHUNK)*NV + t*DD + d8*8;
  float g[8];
  #pragma unroll
  for (int j=0;j<8;++j) g[j] = 0.f;
  float pa = 1.f;
  #pragma unroll
  for (int half=0; half<2; ++half){
    uint4 vv[8];
    #pragma unroll
    for (int s=0;s<8;++s) vv[s] = *(const uint4*)(vp + (size_t)(half*8+s)*NV);
    #pragma unroll
    for (int s=0;s<8;++s){
      float a = sAl[(half*8+s)*TT+t], om = 1.f - a;
      const unsigned short* pv = (const unsigned short*)&vv[s];
      union { unsigned short us[8]; uint4 u; } o;
      #pragma unroll
      for (int j=0;j<8;++j){ g[j] = a*g[j] + om*bf2f(pv[j]); o.us[j] = f2bf(g[j]); }
      *(uint4*)&yl[t][s][d8*8] = o.u;
      pa *= a;
    }
    __syncthreads();
    if (t < 4){
      #pragma unroll
      for (int ii=0; ii<2; ++ii){
        int s = t*2 + ii;
        float y[8];
        #pragma unroll
        for (int j=0;j<8;++j) y[j] = 0.f;
        #pragma unroll
        for (int tt=0;tt<TT;++tt){
          uint4 gv = *(const uint4*)&yl[tt][s][d8*8];
          const unsigned short* gp = (const unsigned short*)&gv;
          #pragma unroll
          for (int j=0;j<8;++j) y[j] += bf2f(gp[j]);
        }
        union { unsigned short us[8]; uint4 u; } o;
        #pragma unroll
        for (int j=0;j<8;++j) o.us[j] = f2bf(y[j]);
        *(uint4*)(yloc + (size_t)(b*SS + c*CHUNK + half*8 + s)*DD + d8*8) = o.u;
      }
    }
    __syncthreads();
  }
  float* Lp = L + ((size_t)(b*TT+t)*NCH + c)*DD + d8*8;
  *(float4*)Lp     = (float4){g[0],g[1],g[2],g[3]};
  *(float4*)(Lp+4) = (float4){g[4],g[5],g[6],g[7]};
  if (d8 == 0) PA[(size_t)(b*TT+t)*NCH + c] = pa;
}

// ---------------------------------------------------------------- scan phase B: sequential carry; 20 blocks (b,t,d-half), 16-deep f32 prefetch
__global__ __launch_bounds__(256) void k_scan_b(
    const float* __restrict__ mix,
    const float* __restrict__ h_prev,
    const float* __restrict__ PA,
    const float* __restrict__ L,
    float* __restrict__ Gc)
{
  int blk = blockIdx.x;      // (b*TT + t)*2 + dhalf  (20 blocks)
  int bt = blk >> 1;
  int t = bt % TT, b = bt / TT;
  int d = (blk & 1)*256 + threadIdx.x;
  __shared__ float sP[NCH];
  if (threadIdx.x < NCH) sP[threadIdx.x] = PA[(size_t)bt*NCH + threadIdx.x];
  __syncthreads();
  float carry = 0.f;         // g_init = sum_p mix[p,t]*h_prev[b,p,t,d]
  #pragma unroll
  for (int p=0;p<PP;++p)
    carry += mix[p*TT+t] * h_prev[((size_t)(b*PP+p)*TT + t)*DD + d];
  const float* Lp = L  + (size_t)bt*NCH*DD + d;
  float*       gc = Gc + (size_t)bt*NCH*DD + d;
  float buf[16], nbuf[16];
  #pragma unroll
  for (int j=0;j<16;++j) buf[j] = Lp[(size_t)j*DD];
  for (int c0=0;c0<NCH;c0+=16){
    if (c0+16 < NCH){
      #pragma unroll
      for (int j=0;j<16;++j) nbuf[j] = Lp[(size_t)(c0+16+j)*DD];
    }
    #pragma unroll
    for (int j=0;j<16;++j){
      gc[(size_t)(c0+j)*DD] = carry;
      carry = sP[c0+j]*carry + buf[j];
    }
    #pragma unroll
    for (int j=0;j<16;++j) buf[j] = nbuf[j];
  }
}

// ---------------------------------------------------------------- scan phase C: y(s) = y_loc(s) + sum_t pref_t(s)*carry_t
__global__ __launch_bounds__(256) void k_scan_c(
    const float* __restrict__ alpha,
    const unsigned short* __restrict__ yloc,
    const float* __restrict__ Gc,
    unsigned short* __restrict__ ybf)
{
  int blk = blockIdx.x;           // b*NCH + c
  int c = blk & (NCH-1), b = blk >> 7;
  int tid = threadIdx.x;          // 256 = 4 waves
  int s4 = tid >> 6;              // wave covers steps s4*4 .. s4*4+3
  int d8 = tid & 63;
  __shared__ float sAl[CHUNK*TT];
  if (tid < CHUNK*TT) sAl[tid] = alpha[(size_t)(b*SS + c*CHUNK)*TT + tid];
  __syncthreads();
  float ca[TT][8];
  #pragma unroll
  for (int t=0;t<TT;++t){
    const float* gp = Gc + ((size_t)(b*TT+t)*NCH + c)*DD + d8*8;
    float4 c0 = *(const float4*)gp;
    float4 c1 = *(const float4*)(gp+4);
    ca[t][0]=c0.x; ca[t][1]=c0.y; ca[t][2]=c0.z; ca[t][3]=c0.w;
    ca[t][4]=c1.x; ca[t][5]=c1.y; ca[t][6]=c1.z; ca[t][7]=c1.w;
  }
  float pr[TT];
  #pragma unroll
  for (int t=0;t<TT;++t){
    float p = 1.f;
    for (int j=0;j<s4*4;++j) p *= sAl[j*TT+t];
    pr[t] = p;
  }
  const unsigned short* yp = yloc + (size_t)(b*SS + c*CHUNK)*DD + d8*8;
  unsigned short* op = ybf + (size_t)(b*SS + c*CHUNK)*DD + d8*8;
  #pragma unroll
  for (int i=0;i<4;++i){
    int s2 = s4*4 + i;
    uint4 yv = *(const uint4*)(yp + (size_t)s2*DD);
    const unsigned short* yq = (const unsigned short*)&yv;
    float y[8];
    #pragma unroll
    for (int j=0;j<8;++j) y[j] = bf2f(yq[j]);
    #pragma unroll
    for (int t=0;t<TT;++t){
      pr[t] *= sAl[s2*TT+t];
      #pragma unroll
      for (int j=0;j<8;++j) y[j] += pr[t]*ca[t][j];
    }
    union { unsigned short us[8]; uint4 u; } o;
    #pragma unroll
    for (int j=0;j<8;++j) o.us[j] = f2bf(y[j]);
    *(uint4*)(op + (size_t)s2*DD) = o.u;
  }
}

// ----------------------------------------------------------------
extern "C" void kernel_launch(void* const* d_in, const int* in_sizes, int n_in,
                              void* d_out, int out_size, void* d_ws, size_t ws_size,
                              hipStream_t stream)
{
  (void)in_sizes; (void)n_in; (void)out_size; (void)ws_size;
  const float* hs     = (const float*)d_in[0];
  const float* gamma  = (const float*)d_in[1];
  const float* beta   = (const float*)d_in[2];
  const float* W_in   = (const float*)d_in[3];
  const float* b_in   = (const float*)d_in[4];
  const float* W1     = (const float*)d_in[5];
  const float* b1     = (const float*)d_in[6];
  const float* W2     = (const float*)d_in[7];
  const float* b2     = (const float*)d_in[8];
  const float* ltau   = (const float*)d_in[9];
  const float* mix    = (const float*)d_in[10];
  const float* W_out  = (const float*)d_in[11];
  const float* b_out  = (const float*)d_in[12];
  const float* scale  = (const float*)d_in[13];
  const float* h_prev = (const float*)d_in[14];
  float* out = (float*)d_out;

  uint8_t* w = (uint8_t*)d_ws;
  unsigned short* xn   = (unsigned short*)(w);                  //  4,194,304 (reused as y_loc)
  unsigned short* WvT  = (unsigned short*)(w + 4194304);        //  2,621,440
  unsigned short* WoT  = (unsigned short*)(w + 6815744);        //    524,288
  float* alphaB        = (float*)(w + 7340032);                 //     81,920
  float* b_v           = (float*)(w + 7421952);                 //     10,240
  float* PA            = (float*)(w + 7432192);                 //      5,120
  float* L             = (float*)(w + 7437312);                 //  2,621,440
  float* Gc            = (float*)(w + 10058752);                //  2,621,440
  unsigned short* vg   = (unsigned short*)(w + 12680192);       // 20,971,520
  unsigned short* ybf  = (unsigned short*)(w + 33651712);       //  4,194,304
  unsigned short* yloc = xn;    // aliased: xn dead after gemm1

  hipLaunchKernelGGL(k_prep_ln, dim3(1344), dim3(256), 0, stream,
                     hs, gamma, beta, W_in, b_in, mix, W_out, W1, b1, W2, b2, ltau,
                     xn, WvT, b_v, WoT, alphaB);
  hipLaunchKernelGGL((k_gemm<128,NV,false>), dim3(NV/128, MM/128), dim3(256), 0, stream,
                     xn, WvT, b_v, nullptr, nullptr, nullptr, vg);
  hipLaunchKernelGGL(k_scan_a, dim3(BB*NCH), dim3(320), 0, stream, alphaB, vg, L, PA, yloc);
  hipLaunchKernelGGL(k_scan_b, dim3(2*BB*TT), dim3(256), 0, stream, mix, h_prev, PA, L, Gc);
  hipLaunchKernelGGL(k_scan_c, dim3(BB*NCH), dim3(256), 0, stream, alphaB, yloc, Gc, ybf);
  hipLaunchKernelGGL((k_gemm<64,DD,true>), dim3(DD/64, MM/128), dim3(256), 0, stream,
                     ybf, WoT, b_out, hs, scale, out, nullptr);
}